// Round 6
// baseline (455.712 us; speedup 1.0000x reference)
//
#include <hip/hip_runtime.h>
#include <stdint.h>

// Problem constants (fixed by reference: L=1024, B=8, D=2048)
#define L_SEQ 1024
#define BATCH 8
#define DIM   2048
#define GM    8192   // L*B
#define GN    6144   // 3*D
#define GK    2048   // D
#define SCALE_X 1.7320508075688772f  // sqrt(1 + 2*exp(0))
#define SCAN_PF 16

// GEMM geometry: 256x256 tile, 8 waves (2M x 4N), k-ring of 4 slices of 32
#define BM 256
#define BN 256
#define BKC 32

using bf16x8  = __attribute__((ext_vector_type(8))) __bf16;
using floatx4 = __attribute__((ext_vector_type(4))) float;

__device__ __forceinline__ unsigned short f2bf(float f) {
  unsigned u = __float_as_uint(f);
  u += 0x7FFFu + ((u >> 16) & 1u);   // round-to-nearest-even
  return (unsigned short)(u >> 16);
}
__device__ __forceinline__ float sigmoidf_fast(float z) {
  return __builtin_amdgcn_rcpf(1.0f + __expf(-z));
}
__device__ __forceinline__ void async16(const unsigned short* g, unsigned short* l) {
  __builtin_amdgcn_global_load_lds(
      (__attribute__((address_space(1))) unsigned int*)g,
      (__attribute__((address_space(3))) unsigned int*)l,
      16, 0, 0);
}

// ------------- fused prep: transpose-cast W -> Bt  +  cast x -> A (bf16) --------
// Blocks [0, 3072): 64x64 transpose tiles (n-tile = blk%96, k-tile = blk/96).
//   Reads W via float4 (16B/lane); writes Bt rows as 8x 16B ushort8 chunks ->
//   each 8-thread group covers one full 128-B line (no partial-line RMW).
// Blocks [3072, 7168): grid-stride streaming cast of x.
// W col n = 3d+j -> j==0: Bt row d (u0 plane); j>0: Bt row DIM + 2d + (j-1).
__global__ __launch_bounds__(256) void prep_kernel(const float4* __restrict__ xin,
                                                   unsigned short* __restrict__ Aout,
                                                   const float* __restrict__ W,
                                                   unsigned short* __restrict__ Bt) {
  __shared__ float tile[64][65];
  const int blk = blockIdx.x;
  if (blk < 3072) {
    const int tx = threadIdx.x & 15, ty = threadIdx.x >> 4;
    const int n0 = (blk % 96) * 64;
    const int k0 = (blk / 96) * 64;
#pragma unroll
    for (int p = 0; p < 4; ++p) {
      const float4 v = *(const float4*)&W[(size_t)(k0 + ty + 16 * p) * GN + n0 + tx * 4];
      float* t = &tile[ty + 16 * p][tx * 4];
      t[0] = v.x; t[1] = v.y; t[2] = v.z; t[3] = v.w;
    }
    __syncthreads();
#pragma unroll
    for (int p = 0; p < 2; ++p) {
      const int jl = (threadIdx.x >> 3) + 32 * p;          // 0..63 n-local
      const int n = n0 + jl;
      const int dq = n / 3, j3 = n - 3 * dq;
      const int np = (j3 == 0) ? dq : (DIM + 2 * dq + (j3 - 1));
      const int klb = (threadIdx.x & 7) * 8;               // 0..56 k-local
      union { unsigned short s[8]; uint4 q; } o;
#pragma unroll
      for (int kk = 0; kk < 8; ++kk) o.s[kk] = f2bf(tile[klb + kk][jl]);
      *(uint4*)&Bt[(size_t)np * GK + k0 + klb] = o.q;
    }
  } else {
    const int n4 = (GM * GK) / 4;
    for (int i = (blk - 3072) * 256 + threadIdx.x; i < n4; i += 4096 * 256) {
      float4 v = xin[i];
      union { unsigned short s[4]; unsigned long long ll; } o;
      o.s[0] = f2bf(v.x); o.s[1] = f2bf(v.y); o.s[2] = f2bf(v.z); o.s[3] = f2bf(v.w);
      *(unsigned long long*)&Aout[(size_t)i * 4] = o.ll;
    }
  }
}

// ---------------- GEMM: U = A(GM x GK) * Bt(GN x GK)^T, bf16 out ----------------
// 256x256 tile, 8 waves (2M x 4N), per-wave 128x64 = 8x4 reps of 16x16x32 MFMA.
// LDS = ring of 4 k-slices (k=32 each) per matrix: 4*16KB*2 = 128 KB, 1 blk/CU.
//
// Merged 2-chunk bodies (this round): each body covers K=64 (slices SL0, SL0+1)
// with FOUR barriers (was 8): WAITV ; BAR0 ; R0(12 ds_read, slice SL0) +
// stage chunk C0+2 -> slot SL0^2 ; BAR1 ; lgkm0 ; 32 MFMA ; BAR2 ;
// R1(12 ds_read, slice SL0+1) + stage C0+3 -> slot SL0^2+1 ; BAR3 ; lgkm0 ;
// 32 MFMA. Stage targets the slice pair read by the PREVIOUS body: all its
// ds_reads completed before each wave's lgkm0, which precedes this body's BAR0
// -> race-free. Prefetch distance = 1 body (~4900 cyc >> 900-cyc HBM latency)
// so the WAITV(0) at entry is instantly satisfied in steady state.
// Per-acc k-order unchanged (ascending chunks) -> bit-identical numerics.
//
// LDS swizzle: 16B slot S(row,s) = (row>>1)*8 + (((row&1)*4+s)^((row>>1)&7));
// applied on ds_read addr, inverted on per-thread GLOBAL source (LDS dest of
// global_load_lds stays lane-linear). Worst case 2-way on ds_read_b128 (free).
// XCD-rectangle swizzle: f -> xcd=f&7, rnd, ss -> 4y x 8x rectangles per XCD
// (A working set 4 MB fits per-XCD L2; FETCH 176->148 MB measured).

#define WAITV(N) asm volatile("s_waitcnt vmcnt(" #N ")" ::: "memory")
#define LGKM0 asm volatile("s_waitcnt lgkmcnt(0)" ::: "memory"); \
              __builtin_amdgcn_sched_barrier(0)

#define CHUNK2(C0, SL0, DOSTAGE)                                              \
  {                                                                           \
    __builtin_amdgcn_s_barrier();  /* BAR0 */                                 \
    __builtin_amdgcn_sched_barrier(0);                                        \
    const char* aB0_ = AsB + (SL0) * 16384;                                   \
    const char* bB0_ = BsB + (SL0) * 16384;                                   \
    const char* aB1_ = AsB + ((SL0) + 1) * 16384;                             \
    const char* bB1_ = BsB + ((SL0) + 1) * 16384;                             \
    bf16x8 bF[4], aF[8];                                                      \
    _Pragma("unroll") for (int nt = 0; nt < 4; ++nt)                          \
        bF[nt] = *(const bf16x8*)(bB0_ + SB0 + nt * 1024);                    \
    _Pragma("unroll") for (int mt = 0; mt < 8; ++mt)                          \
        aF[mt] = *(const bf16x8*)(aB0_ + SA0 + mt * 1024);                    \
    if (DOSTAGE) {                                                            \
      unsigned short* ad_ = (unsigned short*)(AsL + ((SL0) ^ 2) * 16384);     \
      unsigned short* bd_ = (unsigned short*)(BsL + ((SL0) ^ 2) * 16384);     \
      const int ko_ = ((C0) + 2) * BKC;                                       \
      async16(aG0 + ko_, ad_ + L0 * 8);                                       \
      async16(aG1 + ko_, ad_ + L1 * 8);                                       \
      async16(bG0 + ko_, bd_ + L0 * 8);                                       \
      async16(bG1 + ko_, bd_ + L1 * 8);                                       \
    }                                                                         \
    __builtin_amdgcn_sched_barrier(0);                                        \
    __builtin_amdgcn_s_barrier();  /* BAR1 */                                 \
    LGKM0;                                                                    \
    __builtin_amdgcn_s_setprio(1);                                            \
    _Pragma("unroll") for (int mt = 0; mt < 8; ++mt)                          \
      _Pragma("unroll") for (int nt = 0; nt < 4; ++nt)                        \
        acc[mt][nt] = __builtin_amdgcn_mfma_f32_16x16x32_bf16(                \
            aF[mt], bF[nt], acc[mt][nt], 0, 0, 0);                            \
    __builtin_amdgcn_s_setprio(0);                                            \
    __builtin_amdgcn_sched_barrier(0);                                        \
    __builtin_amdgcn_s_barrier();  /* BAR2 */                                 \
    _Pragma("unroll") for (int nt = 0; nt < 4; ++nt)                          \
        bF[nt] = *(const bf16x8*)(bB1_ + SB0 + nt * 1024);                    \
    _Pragma("unroll") for (int mt = 0; mt < 8; ++mt)                          \
        aF[mt] = *(const bf16x8*)(aB1_ + SA0 + mt * 1024);                    \
    if (DOSTAGE) {                                                            \
      unsigned short* ad_ = (unsigned short*)(AsL + (((SL0) ^ 2) + 1) * 16384);\
      unsigned short* bd_ = (unsigned short*)(BsL + (((SL0) ^ 2) + 1) * 16384);\
      const int ko_ = ((C0) + 3) * BKC;                                       \
      async16(aG0 + ko_, ad_ + L0 * 8);                                       \
      async16(aG1 + ko_, ad_ + L1 * 8);                                       \
      async16(bG0 + ko_, bd_ + L0 * 8);                                       \
      async16(bG1 + ko_, bd_ + L1 * 8);                                       \
    }                                                                         \
    __builtin_amdgcn_sched_barrier(0);                                        \
    __builtin_amdgcn_s_barrier();  /* BAR3 */                                 \
    LGKM0;                                                                    \
    __builtin_amdgcn_s_setprio(1);                                            \
    _Pragma("unroll") for (int mt = 0; mt < 8; ++mt)                          \
      _Pragma("unroll") for (int nt = 0; nt < 4; ++nt)                        \
        acc[mt][nt] = __builtin_amdgcn_mfma_f32_16x16x32_bf16(                \
            aF[mt], bF[nt], acc[mt][nt], 0, 0, 0);                            \
    __builtin_amdgcn_s_setprio(0);                                            \
    __builtin_amdgcn_sched_barrier(0);                                        \
  }

__global__ __launch_bounds__(512, 2) void gemm_kernel(const unsigned short* __restrict__ A,
                                                      const unsigned short* __restrict__ Bt,
                                                      unsigned short* __restrict__ U) {
  __shared__ alignas(16) unsigned short As[4][BM * BKC];  // 64 KB
  __shared__ alignas(16) unsigned short Bs[4][BN * BKC];  // 64 KB
  const int tid  = threadIdx.x;
  const int wave = tid >> 6, lane = tid & 63;
  const int quad = lane >> 4, lrow = lane & 15;
  const int wm = (wave >> 2) * 128;  // 2 M-waves
  const int wn = (wave & 3) * 64;    // 4 N-waves

  // XCD-rectangle swizzle: 768 blocks = 8 XCD x 3 rounds x 32 slots (4y x 8x)
  const int f    = blockIdx.y * (GN / BN) + blockIdx.x;
  const int xcd  = f & 7;
  const int slot = f >> 3;
  const int rnd  = slot >> 5;        // 0..2
  const int ss   = slot & 31;        // 0..31
  const int mBase = (4 * xcd + (ss & 3)) * BM;   // y-tile 0..31
  const int nBase = (8 * rnd + (ss >> 2)) * BN;  // x-tile 0..23

  floatx4 acc[8][4] = {};

  // staging: thread owns 16B slots L0=tid, L1=tid+512 of each slice (lane-linear
  // LDS dest). Invert swizzle to find the (row, k-slot) this slot must hold.
  const int L0 = tid, L1 = tid + 512;
  int r0, s0, r1, s1;
  { const int p = L0 >> 3, w = L0 & 7, v = w ^ (p & 7); r0 = 2 * p + (v >> 2); s0 = v & 3; }
  { const int p = L1 >> 3, w = L1 & 7, v = w ^ (p & 7); r1 = 2 * p + (v >> 2); s1 = v & 3; }
  const unsigned short* aG0 = A  + (size_t)(mBase + r0) * GK + s0 * 8;
  const unsigned short* aG1 = A  + (size_t)(mBase + r1) * GK + s1 * 8;
  const unsigned short* bG0 = Bt + (size_t)(nBase + r0) * GK + s0 * 8;
  const unsigned short* bG1 = Bt + (size_t)(nBase + r1) * GK + s1 * 8;

  // ds_read byte offsets within a slice (+16 rows = +1024 B)
  const int rA = wm + lrow;
  const int SA0 = (rA >> 1) * 128 + ((((rA & 1) * 4 + quad) ^ ((rA >> 1) & 7)) * 16);
  const int rB = wn + lrow;
  const int SB0 = (rB >> 1) * 128 + ((((rB & 1) * 4 + quad) ^ ((rB >> 1) & 7)) * 16);
  const char* AsB = (const char*)As;
  const char* BsB = (const char*)Bs;
  char* AsL = (char*)As;
  char* BsL = (char*)Bs;

  // prologue: stage chunks 0..3 (16 loads/thread in flight)
#pragma unroll
  for (int c = 0; c < 4; ++c) {
    unsigned short* ad = (unsigned short*)(AsL + c * 16384);
    unsigned short* bd = (unsigned short*)(BsL + c * 16384);
    async16(aG0 + c * BKC, ad + L0 * 8);
    async16(aG1 + c * BKC, ad + L1 * 8);
    async16(bG0 + c * BKC, bd + L0 * 8);
    async16(bG1 + c * BKC, bd + L1 * 8);
  }

  // bodies: B0 (chunks 0,1; no stage; keep 2,3 in flight), B1..B30 (stage +2,+3),
  // B31 (chunks 62,63; no stage).
  WAITV(8); CHUNK2(0, 0, false);
#pragma unroll 1
  for (int cc = 0; cc < 15; ++cc) {
    const int cb = cc * 4;
    WAITV(0); CHUNK2(cb + 2, 2, true);
    WAITV(0); CHUNK2(cb + 4, 0, true);
  }
  WAITV(0); CHUNK2(62, 2, false);

  // C/D layout: col = lane&15 (N), row = quad*4 + reg (M). Flat U: col = gn.
#pragma unroll
  for (int mt = 0; mt < 8; ++mt) {
    const int gm = mBase + wm + mt * 16 + quad * 4;
#pragma unroll
    for (int nt = 0; nt < 4; ++nt) {
      const int gn = nBase + wn + nt * 16 + lrow;
#pragma unroll
      for (int q = 0; q < 4; ++q)
        U[(size_t)(gm + q) * GN + gn] = f2bf(acc[mt][nt][q]);
    }
  }
}

// ---------------- SRU scan (flat layout: u0 plane, u1u2 interleaved, x in A_bf) -
// U row gm: [u0: d=0..2047][u1u2 interleaved: cols 2048+2d, 2048+2d+1].
// Rotating raw-register prefetch depth 16 -> 48 outstanding vm-ops (<=63 cap).
__global__ __launch_bounds__(64) void sru_scan_flat(const unsigned short* __restrict__ U,
                                                    const unsigned short* __restrict__ xbf,
                                                    const float* __restrict__ c0,
                                                    const float* __restrict__ wc,
                                                    const float* __restrict__ bias,
                                                    float* __restrict__ out) {
  const int e = blockIdx.x * 64 + threadIdx.x;
  const int b = e >> 11, d = e & (DIM - 1);
  const float vf = wc[d], vr = wc[DIM + d];
  const float bfv = bias[d], brv = bias[DIM + d];
  float c = c0[e];

  constexpr int PF = SCAN_PF;
  constexpr int US = BATCH * GN;
  constexpr int XS = BATCH * DIM;

  const unsigned short* u0p  = U + (size_t)b * GN + d;
  const unsigned short* u12p = U + (size_t)b * GN + DIM + 2 * d;
  const unsigned short* xp   = xbf + (size_t)b * DIM + d;
  float* hp = out + (size_t)b * DIM + d;

  unsigned pu0[PF], pu12[PF], pux[PF];
#pragma unroll
  for (int j = 0; j < PF; ++j) {
    pu0[j]  = u0p[(size_t)j * US];
    pu12[j] = *(const unsigned*)(u12p + (size_t)j * US);
    pux[j]  = xp[(size_t)j * XS];
  }
  const unsigned short* uf0  = u0p + (size_t)PF * US;
  const unsigned short* uf12 = u12p + (size_t)PF * US;
  const unsigned short* xf   = xp + (size_t)PF * XS;

  for (int l0 = 0; l0 < L_SEQ; l0 += PF) {
#pragma unroll
    for (int j = 0; j < PF; ++j) {
      const unsigned r0 = pu0[j], r12 = pu12[j], rx = pux[j];
      pu0[j]  = uf0[0];
      pu12[j] = *(const unsigned*)uf12;
      pux[j]  = xf[0];
      uf0 += US; uf12 += US; xf += XS;
      const float a0 = __uint_as_float(r0 << 16);
      const float u1 = __uint_as_float(r12 << 16);
      const float u2 = __uint_as_float(r12 & 0xFFFF0000u);
      const float ax = __uint_as_float(rx << 16) * SCALE_X;
      const float f = sigmoidf_fast(u1 + fmaf(vf, c, bfv));
      c = fmaf(c - a0, f, a0);
      const float rr = sigmoidf_fast(u2 + fmaf(vr, c, brv));
      *hp = fmaf(rr, c - ax, ax);
      hp += XS;
    }
  }
  out[(size_t)L_SEQ * XS + e] = c;
}

// --------------------------------- launcher ------------------------------------
extern "C" void kernel_launch(void* const* d_in, const int* in_sizes, int n_in,
                              void* d_out, int out_size, void* d_ws, size_t ws_size,
                              hipStream_t stream) {
  const float* x    = (const float*)d_in[0];
  const float* c0   = (const float*)d_in[1];
  const float* W    = (const float*)d_in[2];
  const float* wc   = (const float*)d_in[3];
  const float* bias = (const float*)d_in[4];
  float* out = (float*)d_out;

  char* ws = (char*)d_ws;
  // flat layout: A 33,554,432 (+512K scan-overread pad) | Bt 25,165,824 |
  //              U 100,663,296 (+2M scan-overread pad)
  unsigned short* A_bf  = (unsigned short*)(ws);
  unsigned short* Bt_bf = (unsigned short*)(ws + 34078720);
  unsigned short* U_bf  = (unsigned short*)(ws + 59244544);

  prep_kernel<<<7168, 256, 0, stream>>>((const float4*)x, A_bf, W, Bt_bf);
  gemm_kernel<<<dim3(GN / BN, GM / BM), 512, 0, stream>>>(A_bf, Bt_bf, U_bf);
  sru_scan_flat<<<256, 64, 0, stream>>>(U_bf, A_bf, c0, wc, bias, out);
}

// Round 7
// 445.742 us; speedup vs baseline: 1.0224x; 1.0224x over previous
//
#include <hip/hip_runtime.h>
#include <stdint.h>

// Problem constants (fixed by reference: L=1024, B=8, D=2048)
#define L_SEQ 1024
#define BATCH 8
#define DIM   2048
#define GM    8192   // L*B
#define GN    6144   // 3*D
#define GK    2048   // D
#define SCALE_X 1.7320508075688772f  // sqrt(1 + 2*exp(0))
#define SCAN_PF 16

// GEMM geometry: 256x256 tile, 8 waves (2M x 4N), k-ring of 4 slices of 32
#define BM 256
#define BN 256
#define BKC 32

using bf16x8   = __attribute__((ext_vector_type(8))) __bf16;
using floatx4  = __attribute__((ext_vector_type(4))) float;
using floatx16 = __attribute__((ext_vector_type(16))) float;

__device__ __forceinline__ unsigned short f2bf(float f) {
  unsigned u = __float_as_uint(f);
  u += 0x7FFFu + ((u >> 16) & 1u);   // round-to-nearest-even
  return (unsigned short)(u >> 16);
}
__device__ __forceinline__ float sigmoidf_fast(float z) {
  return __builtin_amdgcn_rcpf(1.0f + __expf(-z));
}
__device__ __forceinline__ void async16(const unsigned short* g, unsigned short* l) {
  __builtin_amdgcn_global_load_lds(
      (__attribute__((address_space(1))) unsigned int*)g,
      (__attribute__((address_space(3))) unsigned int*)l,
      16, 0, 0);
}

// ------------- fused prep: transpose-cast W -> Bt  +  cast x -> A (bf16) --------
// Blocks [0, 3072): 64x64 transpose tiles (n-tile = blk%96, k-tile = blk/96).
//   Reads W via float4 (16B/lane); writes Bt rows as 8x 16B ushort8 chunks ->
//   each 8-thread group covers one full 128-B line (no partial-line RMW).
// Blocks [3072, 7168): grid-stride streaming cast of x.
// W col n = 3d+j -> j==0: Bt row d (u0 plane); j>0: Bt row DIM + 2d + (j-1).
__global__ __launch_bounds__(256) void prep_kernel(const float4* __restrict__ xin,
                                                   unsigned short* __restrict__ Aout,
                                                   const float* __restrict__ W,
                                                   unsigned short* __restrict__ Bt) {
  __shared__ float tile[64][65];
  const int blk = blockIdx.x;
  if (blk < 3072) {
    const int tx = threadIdx.x & 15, ty = threadIdx.x >> 4;
    const int n0 = (blk % 96) * 64;
    const int k0 = (blk / 96) * 64;
#pragma unroll
    for (int p = 0; p < 4; ++p) {
      const float4 v = *(const float4*)&W[(size_t)(k0 + ty + 16 * p) * GN + n0 + tx * 4];
      float* t = &tile[ty + 16 * p][tx * 4];
      t[0] = v.x; t[1] = v.y; t[2] = v.z; t[3] = v.w;
    }
    __syncthreads();
#pragma unroll
    for (int p = 0; p < 2; ++p) {
      const int jl = (threadIdx.x >> 3) + 32 * p;          // 0..63 n-local
      const int n = n0 + jl;
      const int dq = n / 3, j3 = n - 3 * dq;
      const int np = (j3 == 0) ? dq : (DIM + 2 * dq + (j3 - 1));
      const int klb = (threadIdx.x & 7) * 8;               // 0..56 k-local
      union { unsigned short s[8]; uint4 q; } o;
#pragma unroll
      for (int kk = 0; kk < 8; ++kk) o.s[kk] = f2bf(tile[klb + kk][jl]);
      *(uint4*)&Bt[(size_t)np * GK + k0 + klb] = o.q;
    }
  } else {
    const int n4 = (GM * GK) / 4;
    for (int i = (blk - 3072) * 256 + threadIdx.x; i < n4; i += 4096 * 256) {
      float4 v = xin[i];
      union { unsigned short s[4]; unsigned long long ll; } o;
      o.s[0] = f2bf(v.x); o.s[1] = f2bf(v.y); o.s[2] = f2bf(v.z); o.s[3] = f2bf(v.w);
      *(unsigned long long*)&Aout[(size_t)i * 4] = o.ll;
    }
  }
}

// ---------------- GEMM: U = A(GM x GK) * Bt(GN x GK)^T, bf16 out ----------------
// 256x256 tile, 8 waves (2M x 4N), per-wave 128x64 via 4x2 tiles of 32x32 MFMA
// (v_mfma_f32_32x32x16_bf16: m119 2495 TF vs ~2176 for 16x16 -> MFMA floor
// 1242 -> 1033 cyc/chunk/CU, and half the MFMA instruction count).
// LDS = ring of 4 k-slices (k=32 each) per matrix: 4*16KB*2 = 128 KB, 1 blk/CU.
//
// Round-4 strict alternation schedule (best measured: 197us / 46.7% MfmaUtil),
// per chunk c: WAITV(8) ; BAR0 ; R0(6 ds_read, kstep0) + stageA(c+3) ; BAR1 ;
// lgkm0 ; 8 MFMA (t=0) ; BAR2 ; R1(6 ds_read, kstep1) + stageB(c+3) ; BAR3 ;
// lgkm0 ; 8 MFMA (t=1). WAITV(8) waits only chunk c's 4 loads, issued 3 chunks
// (~7400 cyc) earlier -> instantly satisfied (round-5's WAITV(0) on half-body-
// old loads was the regression). vmcnt never 0 in main loop; tail peels 8/4/0.
// K-order ascending (t=0 then t=1 into same acc) as before.
//
// Fragment layouts (32x32x16 bf16): A/B lane l holds row m=l&31, k-octet
// 2t+(l>>5) (8 bf16 = 1 swizzled 16B slot); C/D col=lane&31, row=(reg&3)+
// 8*(reg>>2)+4*(lane>>5) [verified m74/m101].
// LDS swizzle: 16B slot S(row,s) = (row>>1)*8 + (((row&1)*4+s)^((row>>1)&7));
// storage side unchanged (inverse applied on global source, LDS dest linear);
// 32x32 read pattern stays <=2-way on ds_read_b128 (free, m136).
// XCD-rectangle swizzle: f -> xcd=f&7, rnd, ss -> 4y x 8x rectangles per XCD
// (A working set 4 MB fits per-XCD L2; FETCH 176->148 MB measured).

#define WAITV(N) asm volatile("s_waitcnt vmcnt(" #N ")" ::: "memory")
#define LGKM0 asm volatile("s_waitcnt lgkmcnt(0)" ::: "memory"); \
              __builtin_amdgcn_sched_barrier(0)

#define CHUNK(cexpr, SL, DOSTAGE)                                             \
  {                                                                           \
    __builtin_amdgcn_s_barrier();  /* BAR0 */                                 \
    __builtin_amdgcn_sched_barrier(0);                                        \
    const int c_ = (cexpr);                                                   \
    const char* aB_ = AsB + (SL) * 16384;                                     \
    const char* bB_ = BsB + (SL) * 16384;                                     \
    bf16x8 bF[2], aF[4];                                                      \
    bF[0] = *(const bf16x8*)(bB_ + SB32_0);                                   \
    bF[1] = *(const bf16x8*)(bB_ + SB32_0 + 2048);                            \
    _Pragma("unroll") for (int mt = 0; mt < 4; ++mt)                          \
        aF[mt] = *(const bf16x8*)(aB_ + SA32_0 + mt * 2048);                  \
    if (DOSTAGE) {                                                            \
      unsigned short* ad_ = (unsigned short*)(AsL + ((c_ + 3) & 3) * 16384);  \
      const int ko_ = (c_ + 3) * BKC;                                         \
      async16(aG0 + ko_, ad_ + L0 * 8);                                       \
      async16(aG1 + ko_, ad_ + L1 * 8);                                       \
    }                                                                         \
    __builtin_amdgcn_sched_barrier(0);                                        \
    __builtin_amdgcn_s_barrier();  /* BAR1: read-burst | MFMA-burst fence */  \
    LGKM0;                                                                    \
    __builtin_amdgcn_s_setprio(1);                                            \
    _Pragma("unroll") for (int mt = 0; mt < 4; ++mt)                          \
      _Pragma("unroll") for (int nt = 0; nt < 2; ++nt)                        \
        acc[mt][nt] = __builtin_amdgcn_mfma_f32_32x32x16_bf16(                \
            aF[mt], bF[nt], acc[mt][nt], 0, 0, 0);                            \
    __builtin_amdgcn_s_setprio(0);                                            \
    __builtin_amdgcn_sched_barrier(0);                                        \
    __builtin_amdgcn_s_barrier();  /* BAR2 */                                 \
    bF[0] = *(const bf16x8*)(bB_ + SB32_1);                                   \
    bF[1] = *(const bf16x8*)(bB_ + SB32_1 + 2048);                            \
    _Pragma("unroll") for (int mt = 0; mt < 4; ++mt)                          \
        aF[mt] = *(const bf16x8*)(aB_ + SA32_1 + mt * 2048);                  \
    if (DOSTAGE) {                                                            \
      unsigned short* bd_ = (unsigned short*)(BsL + ((c_ + 3) & 3) * 16384);  \
      const int ko_ = (c_ + 3) * BKC;                                         \
      async16(bG0 + ko_, bd_ + L0 * 8);                                       \
      async16(bG1 + ko_, bd_ + L1 * 8);                                       \
    }                                                                         \
    __builtin_amdgcn_sched_barrier(0);                                        \
    __builtin_amdgcn_s_barrier();  /* BAR3 */                                 \
    LGKM0;                                                                    \
    __builtin_amdgcn_s_setprio(1);                                            \
    _Pragma("unroll") for (int mt = 0; mt < 4; ++mt)                          \
      _Pragma("unroll") for (int nt = 0; nt < 2; ++nt)                        \
        acc[mt][nt] = __builtin_amdgcn_mfma_f32_32x32x16_bf16(                \
            aF[mt], bF[nt], acc[mt][nt], 0, 0, 0);                            \
    __builtin_amdgcn_s_setprio(0);                                            \
    __builtin_amdgcn_sched_barrier(0);                                        \
  }

__global__ __launch_bounds__(512, 2) void gemm_kernel(const unsigned short* __restrict__ A,
                                                      const unsigned short* __restrict__ Bt,
                                                      unsigned short* __restrict__ U) {
  __shared__ alignas(16) unsigned short As[4][BM * BKC];  // 64 KB
  __shared__ alignas(16) unsigned short Bs[4][BN * BKC];  // 64 KB
  const int tid  = threadIdx.x;
  const int wave = tid >> 6, lane = tid & 63;
  const int wm = (wave >> 2) * 128;  // 2 M-waves
  const int wn = (wave & 3) * 64;    // 4 N-waves

  // XCD-rectangle swizzle: 768 blocks = 8 XCD x 3 rounds x 32 slots (4y x 8x)
  const int f    = blockIdx.y * (GN / BN) + blockIdx.x;
  const int xcd  = f & 7;
  const int slot = f >> 3;
  const int rnd  = slot >> 5;        // 0..2
  const int ss   = slot & 31;        // 0..31
  const int mBase = (4 * xcd + (ss & 3)) * BM;   // y-tile 0..31
  const int nBase = (8 * rnd + (ss >> 2)) * BN;  // x-tile 0..23

  floatx16 acc[4][2] = {};

  // staging: thread owns 16B slots L0=tid, L1=tid+512 of each slice (lane-linear
  // LDS dest). Invert swizzle to find the (row, k-slot) this slot must hold.
  const int L0 = tid, L1 = tid + 512;
  int r0, s0, r1, s1;
  { const int p = L0 >> 3, w = L0 & 7, v = w ^ (p & 7); r0 = 2 * p + (v >> 2); s0 = v & 3; }
  { const int p = L1 >> 3, w = L1 & 7, v = w ^ (p & 7); r1 = 2 * p + (v >> 2); s1 = v & 3; }
  const unsigned short* aG0 = A  + (size_t)(mBase + r0) * GK + s0 * 8;
  const unsigned short* aG1 = A  + (size_t)(mBase + r1) * GK + s1 * 8;
  const unsigned short* bG0 = Bt + (size_t)(nBase + r0) * GK + s0 * 8;
  const unsigned short* bG1 = Bt + (size_t)(nBase + r1) * GK + s1 * 8;

  // ds_read byte offsets for 32x32x16 fragments: lane row = (wm|wn)+(lane&31),
  // k-octet s = 2t + (lane>>5); mt/nt tile stride = 32 rows = 2048 B.
  const int kh = lane >> 5;
  const int rA32 = wm + (lane & 31);
  const int SA32_0 = (rA32 >> 1) * 128 + ((((rA32 & 1) * 4 + 0 + kh) ^ ((rA32 >> 1) & 7)) * 16);
  const int SA32_1 = (rA32 >> 1) * 128 + ((((rA32 & 1) * 4 + 2 + kh) ^ ((rA32 >> 1) & 7)) * 16);
  const int rB32 = wn + (lane & 31);
  const int SB32_0 = (rB32 >> 1) * 128 + ((((rB32 & 1) * 4 + 0 + kh) ^ ((rB32 >> 1) & 7)) * 16);
  const int SB32_1 = (rB32 >> 1) * 128 + ((((rB32 & 1) * 4 + 2 + kh) ^ ((rB32 >> 1) & 7)) * 16);
  const char* AsB = (const char*)As;
  const char* BsB = (const char*)Bs;
  char* AsL = (char*)As;
  char* BsL = (char*)Bs;

  // prologue: stage chunks 0,1,2 (12 loads/thread in flight)
#pragma unroll
  for (int c = 0; c < 3; ++c) {
    unsigned short* ad = (unsigned short*)(AsL + c * 16384);
    unsigned short* bd = (unsigned short*)(BsL + c * 16384);
    async16(aG0 + c * BKC, ad + L0 * 8);
    async16(aG1 + c * BKC, ad + L1 * 8);
    async16(bG0 + c * BKC, bd + L0 * 8);
    async16(bG1 + c * BKC, bd + L1 * 8);
  }

  // main loop: chunks 0..59 (stage c+3), then peeled 60..63
#pragma unroll 1
  for (int cc = 0; cc < 15; ++cc) {
    const int cb = cc * 4;
#pragma unroll
    for (int j = 0; j < 4; ++j) {
      WAITV(8);
      CHUNK(cb + j, j, true);
    }
  }
  WAITV(8); CHUNK(60, 0, true);   // stages chunk 63
  WAITV(8); CHUNK(61, 1, false);
  WAITV(4); CHUNK(62, 2, false);
  WAITV(0); CHUNK(63, 3, false);

  // C/D layout (32x32): col = lane&31 (N), row = (reg&3)+8*(reg>>2)+4*kh (M).
#pragma unroll
  for (int mt = 0; mt < 4; ++mt) {
#pragma unroll
    for (int nt = 0; nt < 2; ++nt) {
      const int gn = nBase + wn + nt * 32 + (lane & 31);
#pragma unroll
      for (int r = 0; r < 16; ++r) {
        const int row = (r & 3) + 8 * (r >> 2) + 4 * kh;
        U[(size_t)(mBase + wm + mt * 32 + row) * GN + gn] = f2bf(acc[mt][nt][r]);
      }
    }
  }
}

// ---------------- SRU scan (flat layout: u0 plane, u1u2 interleaved, x in A_bf) -
// U row gm: [u0: d=0..2047][u1u2 interleaved: cols 2048+2d, 2048+2d+1].
// Rotating raw-register prefetch depth 16 -> 48 outstanding vm-ops (<=63 cap).
__global__ __launch_bounds__(64) void sru_scan_flat(const unsigned short* __restrict__ U,
                                                    const unsigned short* __restrict__ xbf,
                                                    const float* __restrict__ c0,
                                                    const float* __restrict__ wc,
                                                    const float* __restrict__ bias,
                                                    float* __restrict__ out) {
  const int e = blockIdx.x * 64 + threadIdx.x;
  const int b = e >> 11, d = e & (DIM - 1);
  const float vf = wc[d], vr = wc[DIM + d];
  const float bfv = bias[d], brv = bias[DIM + d];
  float c = c0[e];

  constexpr int PF = SCAN_PF;
  constexpr int US = BATCH * GN;
  constexpr int XS = BATCH * DIM;

  const unsigned short* u0p  = U + (size_t)b * GN + d;
  const unsigned short* u12p = U + (size_t)b * GN + DIM + 2 * d;
  const unsigned short* xp   = xbf + (size_t)b * DIM + d;
  float* hp = out + (size_t)b * DIM + d;

  unsigned pu0[PF], pu12[PF], pux[PF];
#pragma unroll
  for (int j = 0; j < PF; ++j) {
    pu0[j]  = u0p[(size_t)j * US];
    pu12[j] = *(const unsigned*)(u12p + (size_t)j * US);
    pux[j]  = xp[(size_t)j * XS];
  }
  const unsigned short* uf0  = u0p + (size_t)PF * US;
  const unsigned short* uf12 = u12p + (size_t)PF * US;
  const unsigned short* xf   = xp + (size_t)PF * XS;

  for (int l0 = 0; l0 < L_SEQ; l0 += PF) {
#pragma unroll
    for (int j = 0; j < PF; ++j) {
      const unsigned r0 = pu0[j], r12 = pu12[j], rx = pux[j];
      pu0[j]  = uf0[0];
      pu12[j] = *(const unsigned*)uf12;
      pux[j]  = xf[0];
      uf0 += US; uf12 += US; xf += XS;
      const float a0 = __uint_as_float(r0 << 16);
      const float u1 = __uint_as_float(r12 << 16);
      const float u2 = __uint_as_float(r12 & 0xFFFF0000u);
      const float ax = __uint_as_float(rx << 16) * SCALE_X;
      const float f = sigmoidf_fast(u1 + fmaf(vf, c, bfv));
      c = fmaf(c - a0, f, a0);
      const float rr = sigmoidf_fast(u2 + fmaf(vr, c, brv));
      *hp = fmaf(rr, c - ax, ax);
      hp += XS;
    }
  }
  out[(size_t)L_SEQ * XS + e] = c;
}

// --------------------------------- launcher ------------------------------------
extern "C" void kernel_launch(void* const* d_in, const int* in_sizes, int n_in,
                              void* d_out, int out_size, void* d_ws, size_t ws_size,
                              hipStream_t stream) {
  const float* x    = (const float*)d_in[0];
  const float* c0   = (const float*)d_in[1];
  const float* W    = (const float*)d_in[2];
  const float* wc   = (const float*)d_in[3];
  const float* bias = (const float*)d_in[4];
  float* out = (float*)d_out;

  char* ws = (char*)d_ws;
  // flat layout: A 33,554,432 (+512K scan-overread pad) | Bt 25,165,824 |
  //              U 100,663,296 (+2M scan-overread pad)
  unsigned short* A_bf  = (unsigned short*)(ws);
  unsigned short* Bt_bf = (unsigned short*)(ws + 34078720);
  unsigned short* U_bf  = (unsigned short*)(ws + 59244544);

  prep_kernel<<<7168, 256, 0, stream>>>((const float4*)x, A_bf, W, Bt_bf);
  gemm_kernel<<<dim3(GN / BN, GM / BM), 512, 0, stream>>>(A_bf, Bt_bf, U_bf);
  sru_scan_flat<<<256, 64, 0, stream>>>(U_bf, A_bf, c0, wc, bias, out);
}